// Round 2
// baseline (3671.888 us; speedup 1.0000x reference)
//
#include <hip/hip_runtime.h>

// NSVF render, fused: per-point MLP + per-ray volumetric rendering.
// Layout: one wave (64 lanes) per ray; lane = sample index.
// Weights are wave-uniform -> scalar (s_load) operands on v_fmac_f32.
// Activations: layer input in a fully-unrolled VGPR array; layer handoff
// through LDS in transposed [k][tid] layout (bank = tid%32, conflict-free).

#define NRAYS 8192
#define MAXS  64
#define EMB   32
#define HID   128
#define NPE   27   // 3 + 6*L_VIEW, L_VIEW=4
#define CH    64
#define NT    128  // threads/block = 2 waves = 2 rays; LDS = 128*NT*4 = 64 KB

__device__ __forceinline__ float wave_sum(float v) {
#pragma unroll
  for (int off = 32; off > 0; off >>= 1) v += __shfl_down(v, off, 64);
  return v;  // lane 0 holds the total
}

__device__ __forceinline__ float wave_prefix_excl(float v, int lane) {
  float inc = v;
#pragma unroll
  for (int off = 1; off < 64; off <<= 1) {
    float u = __shfl_up(inc, off, 64);
    if (lane >= off) inc += u;
  }
  return inc - v;
}

// acc[u] += sum_k in[k] * W[k*J + jc + u], in[] constant-indexed (registers).
template <int K>
__device__ __forceinline__ void chunk_fma(const float* __restrict__ W, int J,
                                          int jc, const float* in, float* acc) {
#pragma unroll
  for (int k = 0; k < K; ++k) {
    const float x = in[k];
    const float* Wr = W + k * J + jc;
#pragma unroll
    for (int u = 0; u < 8; ++u) acc[u] = fmaf(x, Wr[u], acc[u]);
  }
}

__global__ __launch_bounds__(NT, 2) void nsvf_render_kernel(
    const float* __restrict__ rays_d, const float* __restrict__ pts,
    const float* __restrict__ t_vals, const float* __restrict__ dists,
    const int* __restrict__ p2v, const float* __restrict__ vox_emb,
    const float* __restrict__ Wpts,
    const float* __restrict__ W1, const float* __restrict__ b1,
    const float* __restrict__ W2, const float* __restrict__ b2,
    const float* __restrict__ Wsig, const float* __restrict__ bsig,
    const float* __restrict__ Wfeat, const float* __restrict__ bfeat,
    const float* __restrict__ Wc1, const float* __restrict__ bc1,
    const float* __restrict__ Wc2, const float* __restrict__ bc2,
    float* __restrict__ out_rgb, float* __restrict__ out_disp,
    float* __restrict__ out_acc) {
  __shared__ float act[HID][NT];  // transposed: act[k][tid], bank = tid%32

  const int tid  = threadIdx.x;
  const int lane = tid & 63;
  const int ray  = blockIdx.x * (NT / 64) + (tid >> 6);
  const int pidx = ray * MAXS + lane;

  const int vidx = p2v[pidx];
  // counts >= 1, so sample 0 is valid iff ray_hits: derive hit from p2v row 0.
  const bool hit = (__shfl(vidx, 0, 64) >= 0);
  if (!hit) {
    if (lane < 3) out_rgb[ray * 3 + lane] = 0.f;
    if (lane == 0) { out_disp[ray] = 0.f; out_acc[ray] = 0.f; }
    return;
  }
  const bool valid = vidx >= 0;
  const int  gidx  = valid ? vidx : 0;

  // ---- voxel embedding + positional lift: ve = vox_emb[gidx] + pts @ Wpts
  float ve[EMB];
  {
    const float px = pts[pidx * 3 + 0];
    const float py = pts[pidx * 3 + 1];
    const float pz = pts[pidx * 3 + 2];
    const float4* vrow = (const float4*)vox_emb + gidx * (EMB / 4);
    const float4* wp   = (const float4*)Wpts;
#pragma unroll
    for (int e4 = 0; e4 < EMB / 4; ++e4) {
      float4 v  = vrow[e4];
      float4 w0 = wp[e4];
      float4 w1 = wp[EMB / 4 + e4];
      float4 w2 = wp[2 * (EMB / 4) + e4];
      ve[4 * e4 + 0] = v.x + fmaf(px, w0.x, fmaf(py, w1.x, pz * w2.x));
      ve[4 * e4 + 1] = v.y + fmaf(px, w0.y, fmaf(py, w1.y, pz * w2.y));
      ve[4 * e4 + 2] = v.z + fmaf(px, w0.z, fmaf(py, w1.z, pz * w2.z));
      ve[4 * e4 + 3] = v.w + fmaf(px, w0.w, fmaf(py, w1.w, pz * w2.w));
    }
  }

  // ---- layer 1: h1 = relu(ve @ W1 + b1) -> LDS
#pragma unroll 1
  for (int jc = 0; jc < HID; jc += 8) {
    float acc[8];
#pragma unroll
    for (int u = 0; u < 8; ++u) acc[u] = b1[jc + u];
    chunk_fma<EMB>(W1, HID, jc, ve, acc);
#pragma unroll
    for (int u = 0; u < 8; ++u) act[jc + u][tid] = fmaxf(acc[u], 0.f);
  }

  // ---- layer 2: h2 = relu(h1 @ W2 + b2) -> LDS, sigma fused in epilogue
  float x[HID];
#pragma unroll
  for (int k = 0; k < HID; ++k) x[k] = act[k][tid];
  float sigma = bsig[0];
#pragma unroll 1
  for (int jc = 0; jc < HID; jc += 8) {
    float acc[8];
#pragma unroll
    for (int u = 0; u < 8; ++u) acc[u] = b2[jc + u];
    chunk_fma<HID>(W2, HID, jc, x, acc);
#pragma unroll
    for (int u = 0; u < 8; ++u) {
      const float h = fmaxf(acc[u], 0.f);
      act[jc + u][tid] = h;
      sigma = fmaf(h, Wsig[jc + u], sigma);
    }
  }

  // ---- feat = h2 @ Wfeat + bfeat -> LDS
#pragma unroll
  for (int k = 0; k < HID; ++k) x[k] = act[k][tid];
#pragma unroll 1
  for (int jc = 0; jc < HID; jc += 8) {
    float acc[8];
#pragma unroll
    for (int u = 0; u < 8; ++u) acc[u] = bfeat[jc + u];
    chunk_fma<HID>(Wfeat, HID, jc, x, acc);
#pragma unroll
    for (int u = 0; u < 8; ++u) act[jc + u][tid] = acc[u];
  }

  // ---- view positional encoding (wave-uniform values, computed per lane)
  float vemb[NPE];
  {
    const float d0 = rays_d[ray * 3 + 0];
    const float d1 = rays_d[ray * 3 + 1];
    const float d2 = rays_d[ray * 3 + 2];
    vemb[0] = d0; vemb[1] = d1; vemb[2] = d2;
#pragma unroll
    for (int i = 0; i < 3; ++i) {
      const float di = (i == 0) ? d0 : (i == 1) ? d1 : d2;
#pragma unroll
      for (int l = 0; l < 4; ++l) {
        const float ang = di * (float)(1 << l);
        vemb[3 + i * 4 + l]      = __sinf(ang);
        vemb[3 + 12 + i * 4 + l] = __cosf(ang);
      }
    }
  }

  // ---- color head: cc = relu([feat, vemb] @ Wc1 + bc1); rgb = cc @ Wc2 + bc2
  // c2 fused into c1's chunk epilogue (no LDS round-trip for cc).
#pragma unroll
  for (int k = 0; k < HID; ++k) x[k] = act[k][tid];
  float r0 = bc2[0], r1 = bc2[1], r2 = bc2[2];
#pragma unroll 1
  for (int jc = 0; jc < CH; jc += 8) {
    float acc[8];
#pragma unroll
    for (int u = 0; u < 8; ++u) acc[u] = bc1[jc + u];
    chunk_fma<HID>(Wc1, CH, jc, x, acc);
#pragma unroll
    for (int v = 0; v < NPE; ++v) {
      const float* Wr = Wc1 + (HID + v) * CH + jc;
#pragma unroll
      for (int u = 0; u < 8; ++u) acc[u] = fmaf(vemb[v], Wr[u], acc[u]);
    }
#pragma unroll
    for (int u = 0; u < 8; ++u) {
      const float cv = fmaxf(acc[u], 0.f);
      const float* w2r = Wc2 + (jc + u) * 3;
      r0 = fmaf(cv, w2r[0], r0);
      r1 = fmaf(cv, w2r[1], r1);
      r2 = fmaf(cv, w2r[2], r2);
    }
  }

  // ---- volumetric rendering across the wave (lane = sample)
  const float fe   = valid ? fmaxf(sigma, 0.f) * dists[pidx] : 0.f;
  const float pref = wave_prefix_excl(fe, lane);           // cumsum(shifted)
  const float T    = __expf(-pref);
  const float w    = (1.f - __expf(-fe)) * T;              // exactly 0 for invalid lanes
  const float tv   = t_vals[pidx];

  const float crgb0 = wave_sum(w * (r0 + 1.f) * 0.5f);
  const float crgb1 = wave_sum(w * (r1 + 1.f) * 0.5f);
  const float crgb2 = wave_sum(w * (r2 + 1.f) * 0.5f);
  const float accs  = wave_sum(w);
  const float depth = wave_sum(w * tv);

  if (lane == 0) {
    out_rgb[ray * 3 + 0] = crgb0;
    out_rgb[ray * 3 + 1] = crgb1;
    out_rgb[ray * 3 + 2] = crgb2;
    const float disp = 1.f / fmaxf(1e-10f, depth / fmaxf(accs, 1e-10f));
    out_disp[ray] = disp;
    out_acc[ray]  = accs;
  }
}

extern "C" void kernel_launch(void* const* d_in, const int* in_sizes, int n_in,
                              void* d_out, int out_size, void* d_ws, size_t ws_size,
                              hipStream_t stream) {
  // setup_inputs() dict order:
  // 0 rays_d, 1 pts, 2 t_vals, 3 dists, 4 p2v_idx, 5 ray_hits(bool, unused),
  // 6 vox_emb, 7 Wpts, 8 W1, 9 b1, 10 W2, 11 b2, 12 Wsig, 13 bsig,
  // 14 Wfeat, 15 bfeat, 16 Wc1, 17 bc1, 18 Wc2, 19 bc2
  const float* rays_d  = (const float*)d_in[0];
  const float* pts     = (const float*)d_in[1];
  const float* t_vals  = (const float*)d_in[2];
  const float* dists   = (const float*)d_in[3];
  const int*   p2v     = (const int*)d_in[4];
  const float* vox_emb = (const float*)d_in[6];
  const float* Wpts    = (const float*)d_in[7];
  const float* W1      = (const float*)d_in[8];
  const float* b1      = (const float*)d_in[9];
  const float* W2      = (const float*)d_in[10];
  const float* b2      = (const float*)d_in[11];
  const float* Wsig    = (const float*)d_in[12];
  const float* bsig    = (const float*)d_in[13];
  const float* Wfeat   = (const float*)d_in[14];
  const float* bfeat   = (const float*)d_in[15];
  const float* Wc1     = (const float*)d_in[16];
  const float* bc1     = (const float*)d_in[17];
  const float* Wc2     = (const float*)d_in[18];
  const float* bc2     = (const float*)d_in[19];

  float* out      = (float*)d_out;
  float* out_rgb  = out;                 // [8192,3]
  float* out_disp = out + NRAYS * 3;     // [8192]
  float* out_acc  = out + NRAYS * 4;     // [8192]

  dim3 grid(NRAYS / (NT / 64)), block(NT);
  hipLaunchKernelGGL(nsvf_render_kernel, grid, block, 0, stream,
                     rays_d, pts, t_vals, dists, p2v, vox_emb, Wpts,
                     W1, b1, W2, b2, Wsig, bsig, Wfeat, bfeat,
                     Wc1, bc1, Wc2, bc2, out_rgb, out_disp, out_acc);
}

// Round 3
// 736.856 us; speedup vs baseline: 4.9832x; 4.9832x over previous
//
#include <hip/hip_runtime.h>
#include <stdint.h>

// NSVF render, fused. One wave (64 lanes) = one ray; lane = sample.
// Round-3 structure:
//  - feat layer folded away: cc_pre = h2@Wcomb + vemb@WpeT + bcomb (prep kernel)
//  - zero LDS: h1 and cc live in VGPRs with fully-constant indexing;
//    h2 never materialized (chunk-wise scatter into cc)
//  - weights transposed to output-major in d_ws -> contiguous s_load streams

#define NRAYS 8192
#define MAXS  64
#define EMB   32
#define HID   128
#define NPE   27   // 3 + 6*L_VIEW, L_VIEW=4
#define CH    64

// d_ws layout (floats)
#define WS_W1T   0                     // [128][32]   W1T[j*32+k]  = W1[k*128+j]
#define WS_W2T   (WS_W1T + HID*EMB)    // [128][128]  W2T[j*128+k] = W2[k*128+j]
#define WS_WCOMB (WS_W2T + HID*HID)    // [128][64]   Wcomb[m*64+j] = sum_f Wfeat[m,f]*Wc1[f,j]
#define WS_WPE   (WS_WCOMB + HID*CH)   // [64][32]    WpeT[j*32+v] = Wc1[128+v, j] (v<27)
#define WS_BCOMB (WS_WPE + CH*32)      // [64]        bcomb[j] = bc1[j] + sum_f bfeat[f]*Wc1[f,j]
#define WS_TOTAL (WS_BCOMB + CH)       // 30784 floats = 123 KB

__global__ __launch_bounds__(256) void prep_kernel(
    const float* __restrict__ W1, const float* __restrict__ W2,
    const float* __restrict__ Wfeat, const float* __restrict__ bfeat,
    const float* __restrict__ Wc1, const float* __restrict__ bc1,
    float* __restrict__ ws) {
  int idx = blockIdx.x * 256 + threadIdx.x;
  if (idx < HID * EMB) {                       // W1T
    int j = idx >> 5, k = idx & 31;
    ws[WS_W1T + idx] = W1[k * HID + j];
    return;
  }
  idx -= HID * EMB;
  if (idx < HID * HID) {                       // W2T
    int j = idx >> 7, k = idx & 127;
    ws[WS_W2T + idx] = W2[k * HID + j];
    return;
  }
  idx -= HID * HID;
  if (idx < HID * CH) {                        // Wcomb (m-major)
    int m = idx >> 6, j = idx & 63;
    float s = 0.f;
    for (int f = 0; f < HID; ++f) s = fmaf(Wfeat[m * HID + f], Wc1[f * CH + j], s);
    ws[WS_WCOMB + idx] = s;
    return;
  }
  idx -= HID * CH;
  if (idx < CH * 32) {                         // WpeT (row stride 32, padded)
    int j = idx >> 5, v = idx & 31;
    ws[WS_WPE + idx] = (v < NPE) ? Wc1[(HID + v) * CH + j] : 0.f;
    return;
  }
  idx -= CH * 32;
  if (idx < CH) {                              // bcomb
    float s = bc1[idx];
    for (int f = 0; f < HID; ++f) s = fmaf(bfeat[f], Wc1[f * CH + idx], s);
    ws[WS_BCOMB + idx] = s;
  }
}

__device__ __forceinline__ float wave_sum(float v) {
#pragma unroll
  for (int off = 32; off > 0; off >>= 1) v += __shfl_down(v, off, 64);
  return v;  // lane 0 holds the total
}

__device__ __forceinline__ float wave_prefix_excl(float v, int lane) {
  float inc = v;
#pragma unroll
  for (int off = 1; off < 64; off <<= 1) {
    float u = __shfl_up(inc, off, 64);
    if (lane >= off) inc += u;
  }
  return inc - v;
}

__global__ __launch_bounds__(64, 2) void nsvf_main(
    const float* __restrict__ rays_d, const float* __restrict__ pts,
    const float* __restrict__ t_vals, const float* __restrict__ dists,
    const int* __restrict__ p2v, const float* __restrict__ vox_emb,
    const float* __restrict__ Wpts, const float* __restrict__ b1,
    const float* __restrict__ b2, const float* __restrict__ Wsig,
    const float* __restrict__ bsig, const float* __restrict__ Wc2,
    const float* __restrict__ bc2, const float* __restrict__ ws,
    float* __restrict__ out_rgb, float* __restrict__ out_disp,
    float* __restrict__ out_acc) {
  const int lane = threadIdx.x;
  const int ray  = blockIdx.x;
  const int pidx = ray * MAXS + lane;

  const int vidx = p2v[pidx];
  // counts >= 1, so sample 0 is valid iff ray_hits.
  const bool hit = (__shfl(vidx, 0, 64) >= 0);
  if (!hit) {
    if (lane < 3) out_rgb[ray * 3 + lane] = 0.f;
    if (lane == 0) { out_disp[ray] = 0.f; out_acc[ray] = 0.f; }
    return;
  }
  const bool valid = vidx >= 0;
  const int  gidx  = valid ? vidx : 0;

  const float* __restrict__ W1T   = ws + WS_W1T;
  const float* __restrict__ W2T   = ws + WS_W2T;
  const float* __restrict__ Wcomb = ws + WS_WCOMB;
  const float* __restrict__ WpeT  = ws + WS_WPE;
  const float* __restrict__ bcomb = ws + WS_BCOMB;

  // ---- voxel embedding + positional lift: ve = vox_emb[gidx] + pts @ Wpts
  float ve[EMB];
  {
    const float px = pts[pidx * 3 + 0];
    const float py = pts[pidx * 3 + 1];
    const float pz = pts[pidx * 3 + 2];
    const float4* vrow = (const float4*)vox_emb + gidx * (EMB / 4);
    const float4* wp   = (const float4*)Wpts;
#pragma unroll
    for (int e4 = 0; e4 < EMB / 4; ++e4) {
      float4 v  = vrow[e4];
      float4 w0 = wp[e4];
      float4 w1 = wp[EMB / 4 + e4];
      float4 w2 = wp[2 * (EMB / 4) + e4];
      ve[4 * e4 + 0] = v.x + fmaf(px, w0.x, fmaf(py, w1.x, pz * w2.x));
      ve[4 * e4 + 1] = v.y + fmaf(px, w0.y, fmaf(py, w1.y, pz * w2.y));
      ve[4 * e4 + 2] = v.z + fmaf(px, w0.z, fmaf(py, w1.z, pz * w2.z));
      ve[4 * e4 + 3] = v.w + fmaf(px, w0.w, fmaf(py, w1.w, pz * w2.w));
    }
  }

  // ---- layer 1: h1 = relu(ve @ W1 + b1), fully unrolled -> h1 in VGPRs
  float h1[HID];
#pragma unroll
  for (int jc = 0; jc < HID; jc += 8) {
    float a[8];
#pragma unroll
    for (int u = 0; u < 8; ++u) a[u] = b1[jc + u];
#pragma unroll
    for (int k = 0; k < EMB; ++k) {
      const float x = ve[k];
      const float* Wr = W1T + jc * EMB + k;
#pragma unroll
      for (int u = 0; u < 8; ++u) a[u] = fmaf(x, Wr[u * EMB], a[u]);
    }
#pragma unroll
    for (int u = 0; u < 8; ++u) h1[jc + u] = fmaxf(a[u], 0.f);
  }

  // ---- cc init: bcomb + view-PE contribution (vemb regs die after this)
  float cc[CH];
  {
    float vemb[NPE];
    const float d0 = rays_d[ray * 3 + 0];
    const float d1 = rays_d[ray * 3 + 1];
    const float d2 = rays_d[ray * 3 + 2];
    vemb[0] = d0; vemb[1] = d1; vemb[2] = d2;
#pragma unroll
    for (int i = 0; i < 3; ++i) {
      const float di = (i == 0) ? d0 : (i == 1) ? d1 : d2;
#pragma unroll
      for (int l = 0; l < 4; ++l) {
        const float ang = di * (float)(1 << l);
        vemb[3 + i * 4 + l]      = __sinf(ang);
        vemb[3 + 12 + i * 4 + l] = __cosf(ang);
      }
    }
#pragma unroll
    for (int j = 0; j < CH; ++j) {
      float s = bcomb[j];
      const float* Wr = WpeT + j * 32;
#pragma unroll
      for (int v = 0; v < NPE; ++v) s = fmaf(vemb[v], Wr[v], s);
      cc[j] = s;
    }
  }

  // ---- layer 2 fused with sigma head and folded color layer:
  // h2 chunk (8 wide) computed, immediately consumed into sigma and cc, discarded.
  float sigma = bsig[0];
#pragma unroll 1
  for (int jc = 0; jc < HID; jc += 8) {
    float a[8];
#pragma unroll
    for (int u = 0; u < 8; ++u) a[u] = b2[jc + u];
#pragma unroll
    for (int k = 0; k < HID; ++k) {
      const float x = h1[k];
      const float* Wr = W2T + jc * HID + k;
#pragma unroll
      for (int u = 0; u < 8; ++u) a[u] = fmaf(x, Wr[u * HID], a[u]);
    }
    float h2c[8];
#pragma unroll
    for (int u = 0; u < 8; ++u) {
      h2c[u] = fmaxf(a[u], 0.f);
      sigma = fmaf(h2c[u], Wsig[jc + u], sigma);
    }
#pragma unroll
    for (int u = 0; u < 8; ++u) {
      const float hv = h2c[u];
      const float* Cr = Wcomb + (jc + u) * CH;
#pragma unroll
      for (int j = 0; j < CH; ++j) cc[j] = fmaf(hv, Cr[j], cc[j]);
    }
  }

  // ---- color output: rgb = relu(cc) @ Wc2 + bc2
  float r0 = bc2[0], r1 = bc2[1], r2 = bc2[2];
#pragma unroll
  for (int j = 0; j < CH; ++j) {
    const float cv = fmaxf(cc[j], 0.f);
    const float* w2r = Wc2 + j * 3;
    r0 = fmaf(cv, w2r[0], r0);
    r1 = fmaf(cv, w2r[1], r1);
    r2 = fmaf(cv, w2r[2], r2);
  }

  // ---- volumetric rendering across the wave (lane = sample)
  const float fe   = valid ? fmaxf(sigma, 0.f) * dists[pidx] : 0.f;
  const float pref = wave_prefix_excl(fe, lane);           // cumsum(shifted)
  const float T    = __expf(-pref);
  const float w    = (1.f - __expf(-fe)) * T;              // exactly 0 for invalid lanes
  const float tv   = t_vals[pidx];

  const float crgb0 = wave_sum(w * (r0 + 1.f) * 0.5f);
  const float crgb1 = wave_sum(w * (r1 + 1.f) * 0.5f);
  const float crgb2 = wave_sum(w * (r2 + 1.f) * 0.5f);
  const float accs  = wave_sum(w);
  const float depth = wave_sum(w * tv);

  if (lane == 0) {
    out_rgb[ray * 3 + 0] = crgb0;
    out_rgb[ray * 3 + 1] = crgb1;
    out_rgb[ray * 3 + 2] = crgb2;
    const float disp = 1.f / fmaxf(1e-10f, depth / fmaxf(accs, 1e-10f));
    out_disp[ray] = disp;
    out_acc[ray]  = accs;
  }
}

extern "C" void kernel_launch(void* const* d_in, const int* in_sizes, int n_in,
                              void* d_out, int out_size, void* d_ws, size_t ws_size,
                              hipStream_t stream) {
  // setup_inputs() dict order:
  // 0 rays_d, 1 pts, 2 t_vals, 3 dists, 4 p2v_idx, 5 ray_hits(bool, unused),
  // 6 vox_emb, 7 Wpts, 8 W1, 9 b1, 10 W2, 11 b2, 12 Wsig, 13 bsig,
  // 14 Wfeat, 15 bfeat, 16 Wc1, 17 bc1, 18 Wc2, 19 bc2
  const float* rays_d  = (const float*)d_in[0];
  const float* pts     = (const float*)d_in[1];
  const float* t_vals  = (const float*)d_in[2];
  const float* dists   = (const float*)d_in[3];
  const int*   p2v     = (const int*)d_in[4];
  const float* vox_emb = (const float*)d_in[6];
  const float* Wpts    = (const float*)d_in[7];
  const float* W1      = (const float*)d_in[8];
  const float* b1      = (const float*)d_in[9];
  const float* W2      = (const float*)d_in[10];
  const float* b2      = (const float*)d_in[11];
  const float* Wsig    = (const float*)d_in[12];
  const float* bsig    = (const float*)d_in[13];
  const float* Wfeat   = (const float*)d_in[14];
  const float* bfeat   = (const float*)d_in[15];
  const float* Wc1     = (const float*)d_in[16];
  const float* bc1     = (const float*)d_in[17];
  const float* Wc2     = (const float*)d_in[18];
  const float* bc2     = (const float*)d_in[19];

  float* ws = (float*)d_ws;

  float* out      = (float*)d_out;
  float* out_rgb  = out;                 // [8192,3]
  float* out_disp = out + NRAYS * 3;     // [8192]
  float* out_acc  = out + NRAYS * 4;     // [8192]

  const int prep_total = WS_TOTAL;
  hipLaunchKernelGGL(prep_kernel, dim3((prep_total + 255) / 256), dim3(256), 0,
                     stream, W1, W2, Wfeat, bfeat, Wc1, bc1, ws);

  hipLaunchKernelGGL(nsvf_main, dim3(NRAYS), dim3(64), 0, stream,
                     rays_d, pts, t_vals, dists, p2v, vox_emb, Wpts,
                     b1, b2, Wsig, bsig, Wc2, bc2, ws,
                     out_rgb, out_disp, out_acc);
}

// Round 4
// 399.486 us; speedup vs baseline: 9.1915x; 1.8445x over previous
//
#include <hip/hip_runtime.h>
#include <stdint.h>

// NSVF render. Round-4 structure:
//  - valid-point compaction (~46% of lanes are valid -> ~2x less MLP work)
//  - per-ray view-PE precomputed (ccinit) -> removes 1.7K MAC/pt
//  - MLP kernel: thread = compacted point, weights wave-uniform (s_load),
//    h1/cc in VGPRs, h2 never materialized (round-3 inner loops unchanged)
//  - render kernel: wave = ray, prefix-scan over samples

#define NRAYS 8192
#define MAXS  64
#define EMB   32
#define HID   128
#define NPE   27   // 3 + 6*L_VIEW, L_VIEW=4
#define CH    64
#define NPTS  (NRAYS * MAXS)

// d_ws layout (float indices)
#define WS_W1T    0                        // [128][32]  W1T[j*32+k]  = W1[k*128+j]
#define WS_W2T    (WS_W1T + HID*EMB)       // [128][128] W2T[j*128+k] = W2[k*128+j]
#define WS_WCOMB  (WS_W2T + HID*HID)       // [128][64]  Wcomb[m*64+j]
#define WS_WPE    (WS_WCOMB + HID*CH)      // [32][64]   WPE[v*64+j] = Wc1[128+v][j], v-major
#define WS_BCOMB  (WS_WPE + 32*CH)         // [64]
#define WS_CCINIT (WS_BCOMB + CH)          // [8192][64] per-ray cc init
#define WS_COUNTS (WS_CCINIT + NRAYS*CH)   // [8192] int
#define WS_OFFS   (WS_COUNTS + NRAYS)      // [8192] int (exclusive scan)
#define WS_TOTAL  (WS_OFFS + NRAYS)        // [1] int
#define WS_LIST   (WS_TOTAL + 4)           // [524288] int, 16B aligned
#define WS_PTOUT  (WS_LIST + NPTS)         // [524288] float4 (sigma, r, g, b)
#define WS_PREP_N 30784                    // elems written by prep_kernel

__global__ __launch_bounds__(256) void prep_kernel(
    const float* __restrict__ W1, const float* __restrict__ W2,
    const float* __restrict__ Wfeat, const float* __restrict__ bfeat,
    const float* __restrict__ Wc1, const float* __restrict__ bc1,
    float* __restrict__ ws) {
  int idx = blockIdx.x * 256 + threadIdx.x;
  if (idx < HID * EMB) {                       // W1T
    int j = idx >> 5, k = idx & 31;
    ws[WS_W1T + idx] = W1[k * HID + j];
    return;
  }
  idx -= HID * EMB;
  if (idx < HID * HID) {                       // W2T
    int j = idx >> 7, k = idx & 127;
    ws[WS_W2T + idx] = W2[k * HID + j];
    return;
  }
  idx -= HID * HID;
  if (idx < HID * CH) {                        // Wcomb (m-major)
    int m = idx >> 6, j = idx & 63;
    float s = 0.f;
    for (int f = 0; f < HID; ++f) s = fmaf(Wfeat[m * HID + f], Wc1[f * CH + j], s);
    ws[WS_WCOMB + idx] = s;
    return;
  }
  idx -= HID * CH;
  if (idx < 32 * CH) {                         // WPE v-major [v][j]
    int v = idx >> 6, j = idx & 63;
    ws[WS_WPE + idx] = (v < NPE) ? Wc1[(HID + v) * CH + j] : 0.f;
    return;
  }
  idx -= 32 * CH;
  if (idx < CH) {                              // bcomb
    float s = bc1[idx];
    for (int f = 0; f < HID; ++f) s = fmaf(bfeat[f], Wc1[f * CH + idx], s);
    ws[WS_BCOMB + idx] = s;
  }
}

// per-ray cc init: ccinit[ray][j] = bcomb[j] + sum_v vemb[v] * WPE[v][j]
__global__ __launch_bounds__(256) void pe_kernel(
    const float* __restrict__ rays_d, float* __restrict__ ws) {
  const int tid = threadIdx.x;
  const int ray = blockIdx.x * 4 + (tid >> 6);
  const int j   = tid & 63;
  const float d0 = rays_d[ray * 3 + 0];
  const float d1 = rays_d[ray * 3 + 1];
  const float d2 = rays_d[ray * 3 + 2];
  float vemb[NPE];
  vemb[0] = d0; vemb[1] = d1; vemb[2] = d2;
#pragma unroll
  for (int i = 0; i < 3; ++i) {
    const float di = (i == 0) ? d0 : (i == 1) ? d1 : d2;
#pragma unroll
    for (int l = 0; l < 4; ++l) {
      const float ang = di * (float)(1 << l);
      vemb[3 + i * 4 + l]      = __sinf(ang);
      vemb[3 + 12 + i * 4 + l] = __cosf(ang);
    }
  }
  float s = ws[WS_BCOMB + j];
  const float* wpe = ws + WS_WPE;
#pragma unroll
  for (int v = 0; v < NPE; ++v) s = fmaf(vemb[v], wpe[v * CH + j], s);
  ws[WS_CCINIT + ray * CH + j] = s;
}

__global__ __launch_bounds__(256) void count_kernel(
    const int* __restrict__ p2v, float* __restrict__ ws) {
  const int tid = threadIdx.x;
  const int ray = blockIdx.x * 4 + (tid >> 6);
  const int lane = tid & 63;
  const int v = p2v[ray * MAXS + lane];
  const unsigned long long ball = __ballot(v >= 0);
  if (lane == 0) ((int*)(ws + WS_COUNTS))[ray] = __popcll(ball);
}

__global__ __launch_bounds__(1024) void scan_kernel(float* __restrict__ ws) {
  const int* counts = (const int*)(ws + WS_COUNTS);
  int* offs   = (int*)(ws + WS_OFFS);
  int* totalp = (int*)(ws + WS_TOTAL);
  __shared__ int wsum[16];
  const int tid = threadIdx.x;
  const int lane = tid & 63;
  const int base = tid * 8;
  int c[8], e[8];
  int run = 0;
#pragma unroll
  for (int i = 0; i < 8; ++i) { c[i] = counts[base + i]; e[i] = run; run += c[i]; }
  // wave-level exclusive scan of per-thread sums
  int inc = run;
#pragma unroll
  for (int off = 1; off < 64; off <<= 1) {
    int u = __shfl_up(inc, off, 64);
    if (lane >= off) inc += u;
  }
  const int wexcl = inc - run;
  if (lane == 63) wsum[tid >> 6] = inc;
  __syncthreads();
  if (tid < 16) {
    int v = wsum[tid];
    int inc2 = v;
#pragma unroll
    for (int off = 1; off < 16; off <<= 1) {
      int u = __shfl_up(inc2, off, 64);
      if (tid >= off) inc2 += u;
    }
    wsum[tid] = inc2 - v;
    if (tid == 15) totalp[0] = inc2;
  }
  __syncthreads();
  const int wbase = wsum[tid >> 6];
#pragma unroll
  for (int i = 0; i < 8; ++i) offs[base + i] = wbase + wexcl + e[i];
}

__global__ __launch_bounds__(256) void list_kernel(
    const int* __restrict__ p2v, float* __restrict__ ws) {
  const int tid = threadIdx.x;
  const int ray = blockIdx.x * 4 + (tid >> 6);
  const int lane = tid & 63;
  const int pidx = ray * MAXS + lane;
  const bool valid = p2v[pidx] >= 0;
  const unsigned long long ball = __ballot(valid);
  const int rank = __popcll(ball & ((1ull << lane) - 1ull));
  if (valid) {
    const int off = ((const int*)(ws + WS_OFFS))[ray];
    ((int*)(ws + WS_LIST))[off + rank] = pidx;
  }
}

__global__ __launch_bounds__(256, 2) void mlp_kernel(
    const float* __restrict__ pts, const int* __restrict__ p2v,
    const float* __restrict__ vox_emb, const float* __restrict__ Wpts,
    const float* __restrict__ b1, const float* __restrict__ b2,
    const float* __restrict__ Wsig, const float* __restrict__ bsig,
    const float* __restrict__ Wc2, const float* __restrict__ bc2,
    float* __restrict__ ws) {
  const int slot = blockIdx.x * 256 + threadIdx.x;
  const int total = ((const int*)(ws + WS_TOTAL))[0];
  if (slot >= total) return;
  const int pidx = ((const int*)(ws + WS_LIST))[slot];
  const int ray  = pidx >> 6;  // MAXS = 64
  const int gidx = p2v[pidx];  // valid by construction

  const float* __restrict__ W1T   = ws + WS_W1T;
  const float* __restrict__ W2T   = ws + WS_W2T;
  const float* __restrict__ Wcomb = ws + WS_WCOMB;

  // ---- voxel embedding + positional lift
  float ve[EMB];
  {
    const float px = pts[pidx * 3 + 0];
    const float py = pts[pidx * 3 + 1];
    const float pz = pts[pidx * 3 + 2];
    const float4* vrow = (const float4*)vox_emb + gidx * (EMB / 4);
    const float4* wp   = (const float4*)Wpts;
#pragma unroll
    for (int e4 = 0; e4 < EMB / 4; ++e4) {
      float4 v  = vrow[e4];
      float4 w0 = wp[e4];
      float4 w1 = wp[EMB / 4 + e4];
      float4 w2 = wp[2 * (EMB / 4) + e4];
      ve[4 * e4 + 0] = v.x + fmaf(px, w0.x, fmaf(py, w1.x, pz * w2.x));
      ve[4 * e4 + 1] = v.y + fmaf(px, w0.y, fmaf(py, w1.y, pz * w2.y));
      ve[4 * e4 + 2] = v.z + fmaf(px, w0.z, fmaf(py, w1.z, pz * w2.z));
      ve[4 * e4 + 3] = v.w + fmaf(px, w0.w, fmaf(py, w1.w, pz * w2.w));
    }
  }

  // ---- layer 1: h1 = relu(ve @ W1 + b1), fully unrolled
  float h1[HID];
#pragma unroll
  for (int jc = 0; jc < HID; jc += 8) {
    float a[8];
#pragma unroll
    for (int u = 0; u < 8; ++u) a[u] = b1[jc + u];
#pragma unroll
    for (int k = 0; k < EMB; ++k) {
      const float x = ve[k];
      const float* Wr = W1T + jc * EMB + k;
#pragma unroll
      for (int u = 0; u < 8; ++u) a[u] = fmaf(x, Wr[u * EMB], a[u]);
    }
#pragma unroll
    for (int u = 0; u < 8; ++u) h1[jc + u] = fmaxf(a[u], 0.f);
  }

  // ---- cc init from precomputed per-ray PE
  float cc[CH];
  {
    const float4* ci = (const float4*)(ws + WS_CCINIT) + ray * (CH / 4);
#pragma unroll
    for (int j4 = 0; j4 < CH / 4; ++j4) {
      float4 v = ci[j4];
      cc[4 * j4 + 0] = v.x; cc[4 * j4 + 1] = v.y;
      cc[4 * j4 + 2] = v.z; cc[4 * j4 + 3] = v.w;
    }
  }

  // ---- layer 2 fused with sigma head and folded color layer
  float sigma = bsig[0];
#pragma unroll 1
  for (int jc = 0; jc < HID; jc += 8) {
    float a[8];
#pragma unroll
    for (int u = 0; u < 8; ++u) a[u] = b2[jc + u];
#pragma unroll
    for (int k = 0; k < HID; ++k) {
      const float x = h1[k];
      const float* Wr = W2T + jc * HID + k;
#pragma unroll
      for (int u = 0; u < 8; ++u) a[u] = fmaf(x, Wr[u * HID], a[u]);
    }
    float h2c[8];
#pragma unroll
    for (int u = 0; u < 8; ++u) {
      h2c[u] = fmaxf(a[u], 0.f);
      sigma = fmaf(h2c[u], Wsig[jc + u], sigma);
    }
#pragma unroll
    for (int u = 0; u < 8; ++u) {
      const float hv = h2c[u];
      const float* Cr = Wcomb + (jc + u) * CH;
#pragma unroll
      for (int j = 0; j < CH; ++j) cc[j] = fmaf(hv, Cr[j], cc[j]);
    }
  }

  // ---- color output: rgb = relu(cc) @ Wc2 + bc2
  float r0 = bc2[0], r1 = bc2[1], r2 = bc2[2];
#pragma unroll
  for (int j = 0; j < CH; ++j) {
    const float cv = fmaxf(cc[j], 0.f);
    const float* w2r = Wc2 + j * 3;
    r0 = fmaf(cv, w2r[0], r0);
    r1 = fmaf(cv, w2r[1], r1);
    r2 = fmaf(cv, w2r[2], r2);
  }

  ((float4*)(ws + WS_PTOUT))[pidx] = make_float4(sigma, r0, r1, r2);
}

__device__ __forceinline__ float wave_sum(float v) {
#pragma unroll
  for (int off = 32; off > 0; off >>= 1) v += __shfl_down(v, off, 64);
  return v;
}

__device__ __forceinline__ float wave_prefix_excl(float v, int lane) {
  float inc = v;
#pragma unroll
  for (int off = 1; off < 64; off <<= 1) {
    float u = __shfl_up(inc, off, 64);
    if (lane >= off) inc += u;
  }
  return inc - v;
}

__global__ __launch_bounds__(256) void render_kernel(
    const float* __restrict__ t_vals, const float* __restrict__ dists,
    const int* __restrict__ p2v, const float* __restrict__ ws,
    float* __restrict__ out_rgb, float* __restrict__ out_disp,
    float* __restrict__ out_acc) {
  const int tid  = threadIdx.x;
  const int ray  = blockIdx.x * 4 + (tid >> 6);
  const int lane = tid & 63;
  const int pidx = ray * MAXS + lane;

  const int vidx = p2v[pidx];
  const bool hit = (__shfl(vidx, 0, 64) >= 0);
  if (!hit) {
    if (lane < 3) out_rgb[ray * 3 + lane] = 0.f;
    if (lane == 0) { out_disp[ray] = 0.f; out_acc[ray] = 0.f; }
    return;
  }
  const bool valid = vidx >= 0;

  const float4 pv = ((const float4*)(ws + WS_PTOUT))[pidx];  // garbage if invalid; w=0 kills it
  const float fe   = valid ? fmaxf(pv.x, 0.f) * dists[pidx] : 0.f;
  const float pref = wave_prefix_excl(fe, lane);
  const float T    = __expf(-pref);
  const float w    = (1.f - __expf(-fe)) * T;
  const float tv   = t_vals[pidx];

  const float crgb0 = wave_sum(w * (pv.y + 1.f) * 0.5f);
  const float crgb1 = wave_sum(w * (pv.z + 1.f) * 0.5f);
  const float crgb2 = wave_sum(w * (pv.w + 1.f) * 0.5f);
  const float accs  = wave_sum(w);
  const float depth = wave_sum(w * tv);

  if (lane == 0) {
    out_rgb[ray * 3 + 0] = crgb0;
    out_rgb[ray * 3 + 1] = crgb1;
    out_rgb[ray * 3 + 2] = crgb2;
    const float disp = 1.f / fmaxf(1e-10f, depth / fmaxf(accs, 1e-10f));
    out_disp[ray] = disp;
    out_acc[ray]  = accs;
  }
}

extern "C" void kernel_launch(void* const* d_in, const int* in_sizes, int n_in,
                              void* d_out, int out_size, void* d_ws, size_t ws_size,
                              hipStream_t stream) {
  const float* rays_d  = (const float*)d_in[0];
  const float* pts     = (const float*)d_in[1];
  const float* t_vals  = (const float*)d_in[2];
  const float* dists   = (const float*)d_in[3];
  const int*   p2v     = (const int*)d_in[4];
  const float* vox_emb = (const float*)d_in[6];
  const float* Wpts    = (const float*)d_in[7];
  const float* W1      = (const float*)d_in[8];
  const float* b1      = (const float*)d_in[9];
  const float* W2      = (const float*)d_in[10];
  const float* b2      = (const float*)d_in[11];
  const float* Wsig    = (const float*)d_in[12];
  const float* bsig    = (const float*)d_in[13];
  const float* Wfeat   = (const float*)d_in[14];
  const float* bfeat   = (const float*)d_in[15];
  const float* Wc1     = (const float*)d_in[16];
  const float* bc1     = (const float*)d_in[17];
  const float* Wc2     = (const float*)d_in[18];
  const float* bc2     = (const float*)d_in[19];

  float* ws = (float*)d_ws;
  float* out      = (float*)d_out;
  float* out_rgb  = out;
  float* out_disp = out + NRAYS * 3;
  float* out_acc  = out + NRAYS * 4;

  hipLaunchKernelGGL(prep_kernel, dim3((WS_PREP_N + 255) / 256), dim3(256), 0,
                     stream, W1, W2, Wfeat, bfeat, Wc1, bc1, ws);
  hipLaunchKernelGGL(pe_kernel, dim3(NRAYS / 4), dim3(256), 0, stream, rays_d, ws);
  hipLaunchKernelGGL(count_kernel, dim3(NRAYS / 4), dim3(256), 0, stream, p2v, ws);
  hipLaunchKernelGGL(scan_kernel, dim3(1), dim3(1024), 0, stream, ws);
  hipLaunchKernelGGL(list_kernel, dim3(NRAYS / 4), dim3(256), 0, stream, p2v, ws);
  hipLaunchKernelGGL(mlp_kernel, dim3(NPTS / 256), dim3(256), 0, stream,
                     pts, p2v, vox_emb, Wpts, b1, b2, Wsig, bsig, Wc2, bc2, ws);
  hipLaunchKernelGGL(render_kernel, dim3(NRAYS / 4), dim3(256), 0, stream,
                     t_vals, dists, p2v, ws, out_rgb, out_disp, out_acc);
}